// Round 4
// baseline (41.139 us; speedup 1.0000x reference)
//
#include <hip/hip_runtime.h>

// Bidirectional Chamfer distance, fp32, shapes (16, 2048, 3).
//
// Two kernels:
//  1) pack_kernel: both clouds -> float4 (x, y, z, |t|^2) in d_ws.
//  2) chamfer_kernel: 256 blocks = dir(2) x batch(16) x query-chunk(8),
//     1024 threads = 16 waves. Block owns 256 queries (Q=4/lane in regs);
//     wave w scans targets [w*128, w*128+128) with WAVE-UNIFORM loads
//     (readfirstlane-forced SGPR base -> s_load_dwordx4 on the scalar
//     pipe, zero VALU/LDS contention). LDS is used only for the final
//     16-wave min combine.
//
// Math: d2 = |p|^2 + |t|^2 - 2 p.t. Per lane precompute q = -2p; per pair
// d2' = fma(qz,tz, fma(qy,ty, fma(qx,tx, tw))). Two targets share one
// min via fminf(fminf(m,da),db) -> v_min3_f32: 3.5 VALU ops/pair.
// |p|^2 is added after the scan (commutes with min).

#define NPTS  2048
#define BATCH 16

__global__ __launch_bounds__(256) void pack_kernel(
    const float* __restrict__ pred,
    const float* __restrict__ tgt,
    float4* __restrict__ packed)
{
    const int i = blockIdx.x * 256 + threadIdx.x;   // 0 .. 32767
    float x = pred[i * 3 + 0], y = pred[i * 3 + 1], z = pred[i * 3 + 2];
    packed[i] = make_float4(x, y, z, x * x + y * y + z * z);
    x = tgt[i * 3 + 0]; y = tgt[i * 3 + 1]; z = tgt[i * 3 + 2];
    packed[BATCH * NPTS + i] = make_float4(x, y, z, x * x + y * y + z * z);
}

__global__ __launch_bounds__(1024) void chamfer_kernel(
    const float* __restrict__ pred,
    const float* __restrict__ tgt,
    const float4* __restrict__ packed,
    float* __restrict__ out)
{
    const int bid = blockIdx.x;
    const int dir = bid >> 7;          // 0: pred->tgt, 1: tgt->pred
    const int b   = (bid >> 3) & 15;   // batch
    const int qc  = bid & 7;           // query chunk of 256

    const int tid  = threadIdx.x;
    const int lane = tid & 63;
    const int w    = tid >> 6;         // wave 0..15

    // Query cloud: raw float3. Target cloud: packed float4 in ws.
    const float*  Pb = (dir ? tgt : pred) + (size_t)b * NPTS * 3;
    const float4* Tb = packed + (dir ? 0 : BATCH * NPTS) + b * NPTS;

    __shared__ float smin[16][256];    // 16 KB: per-wave partial mins

    // --- Load 4 query points per lane; fold -2 into the query ---
    float qx[4], qy[4], qz[4], pp[4], m0[4], m1[4];
    #pragma unroll
    for (int q = 0; q < 4; ++q) {
        const int qi = qc * 256 + q * 64 + lane;
        const float x = Pb[qi * 3 + 0];
        const float y = Pb[qi * 3 + 1];
        const float z = Pb[qi * 3 + 2];
        qx[q] = -2.0f * x;
        qy[q] = -2.0f * y;
        qz[q] = -2.0f * z;
        pp[q] = x * x + y * y + z * z;
        m0[q] = 3.4e38f;
        m1[q] = 3.4e38f;
    }

    // --- Wave-uniform scan of this wave's 128-target slice ---
    // readfirstlane forces the base into an SGPR so target loads are
    // provably uniform -> scalar (SMEM) loads, off the VALU/LDS pipes.
    const int base = __builtin_amdgcn_readfirstlane(w) * 128;

    #pragma unroll 2
    for (int j = 0; j < 128; j += 4) {
        const float4 ta = Tb[base + j + 0];
        const float4 tb = Tb[base + j + 1];
        const float4 tc = Tb[base + j + 2];
        const float4 td = Tb[base + j + 3];
        #pragma unroll
        for (int q = 0; q < 4; ++q) {
            const float da = fmaf(qz[q], ta.z, fmaf(qy[q], ta.y, fmaf(qx[q], ta.x, ta.w)));
            const float db = fmaf(qz[q], tb.z, fmaf(qy[q], tb.y, fmaf(qx[q], tb.x, tb.w)));
            const float dc = fmaf(qz[q], tc.z, fmaf(qy[q], tc.y, fmaf(qx[q], tc.x, tc.w)));
            const float dd = fmaf(qz[q], td.z, fmaf(qy[q], td.y, fmaf(qx[q], td.x, td.w)));
            m0[q] = fminf(fminf(m0[q], da), db);   // -> v_min3_f32
            m1[q] = fminf(fminf(m1[q], dc), dd);   // -> v_min3_f32
        }
    }

    // --- Cross-wave min combine (add |p|^2 here: commutes with min) ---
    #pragma unroll
    for (int q = 0; q < 4; ++q)
        smin[w][q * 64 + lane] = fminf(m0[q], m1[q]) + pp[q];
    __syncthreads();

    if (tid < 256) {
        float v = smin[0][tid];
        #pragma unroll
        for (int ww = 1; ww < 16; ++ww)
            v = fminf(v, smin[ww][tid]);
        // Sum the 64 query mins in this wave, one atomic per wave.
        #pragma unroll
        for (int off = 32; off > 0; off >>= 1)
            v += __shfl_down(v, off);
        if (lane == 0)
            atomicAdd(out, v * (1.0f / (float)(BATCH * NPTS)));
    }
}

extern "C" void kernel_launch(void* const* d_in, const int* in_sizes, int n_in,
                              void* d_out, int out_size, void* d_ws, size_t ws_size,
                              hipStream_t stream)
{
    const float* pred = (const float*)d_in[0];
    const float* tgt  = (const float*)d_in[1];
    float* out = (float*)d_out;
    float4* packed = (float4*)d_ws;    // 2 * 16 * 2048 * 16 B = 1 MB

    // Harness poisons d_out once and never re-poisons between replays:
    // zero it every call so the atomic accumulation starts clean.
    hipMemsetAsync(out, 0, sizeof(float), stream);

    pack_kernel<<<dim3((BATCH * NPTS) / 256), dim3(256), 0, stream>>>(pred, tgt, packed);
    chamfer_kernel<<<dim3(256), dim3(1024), 0, stream>>>(pred, tgt, packed, out);
}

// Round 5
// 17.720 us; speedup vs baseline: 2.3217x; 2.3217x over previous
//
#include <hip/hip_runtime.h>

// Bidirectional Chamfer distance, fp32, shapes (16, 2048, 3).
//
// chamfer_kernel: 256 blocks = dir(2) x batch(16) x query-chunk(8),
//   1024 threads = 16 waves, 1 block/CU. Block owns 256 queries
//   (Q=4/lane in registers, shared by all waves); wave w scans targets
//   [w*128, (w+1)*128) from a 32 KB LDS float4 tile (x,y,z,|t|^2) via
//   broadcast ds_read_b128 (no bank conflicts). NO atomics: each block
//   writes ONE partial sum to d_ws.
// reduce_kernel: one 256-thread block sums the 256 partials -> out[0].
//   (Eliminates the 1024 same-address atomicAdd storm of R1-R3 and the
//   memset node: out is written with a plain store.)
//
// Math: d2 = |p|^2 + |t|^2 - 2 p.t. Per lane precompute q = -2p; per pair
// d2' = fma(qz,tz, fma(qy,ty, fma(qx,tx, tw))). Two targets fold into one
// min via fminf(fminf(m,da),db) -> v_min3_f32. |p|^2 added after the scan
// (commutes with min).

#define NPTS  2048
#define BATCH 16
#define NBLK  256

__global__ __launch_bounds__(1024) void chamfer_kernel(
    const float* __restrict__ pred,
    const float* __restrict__ tgt,
    float* __restrict__ partial)
{
    const int bid = blockIdx.x;
    const int dir = bid >> 7;          // 0: pred->tgt, 1: tgt->pred
    const int b   = (bid >> 3) & 15;   // batch
    const int qc  = bid & 7;           // query chunk of 256

    const int tid  = threadIdx.x;
    const int lane = tid & 63;
    const int w    = tid >> 6;         // wave 0..15

    const float* __restrict__ P = dir ? tgt  : pred;  // query cloud
    const float* __restrict__ T = dir ? pred : tgt;   // other cloud
    const float* Pb = P + (size_t)b * NPTS * 3;
    const float* Tb = T + (size_t)b * NPTS * 3;

    __shared__ float4 tile[NPTS];      // 32 KB: x, y, z, |t|^2
    __shared__ float  smin[16][256];   // 16 KB: per-wave partial mins
    __shared__ float  spart[4];

    // --- Stage the full target cloud into LDS (2 points per thread) ---
    #pragma unroll
    for (int k = 0; k < 2; ++k) {
        const int idx = tid + k * 1024;
        const float x = Tb[idx * 3 + 0];
        const float y = Tb[idx * 3 + 1];
        const float z = Tb[idx * 3 + 2];
        tile[idx] = make_float4(x, y, z, x * x + y * y + z * z);
    }

    // --- Load 4 query points per lane; fold -2 into the query ---
    float qx[4], qy[4], qz[4], pp[4], m0[4], m1[4];
    #pragma unroll
    for (int q = 0; q < 4; ++q) {
        const int qi = qc * 256 + q * 64 + lane;
        const float x = Pb[qi * 3 + 0];
        const float y = Pb[qi * 3 + 1];
        const float z = Pb[qi * 3 + 2];
        qx[q] = -2.0f * x;
        qy[q] = -2.0f * y;
        qz[q] = -2.0f * z;
        pp[q] = x * x + y * y + z * z;
        m0[q] = 3.4e38f;
        m1[q] = 3.4e38f;
    }

    __syncthreads();

    // --- Scan this wave's 128-target slice (broadcast ds_read_b128) ---
    const int base = w * 128;
    #pragma unroll 2
    for (int j = 0; j < 128; j += 4) {
        const float4 ta = tile[base + j + 0];
        const float4 tb = tile[base + j + 1];
        const float4 tc = tile[base + j + 2];
        const float4 td = tile[base + j + 3];
        #pragma unroll
        for (int q = 0; q < 4; ++q) {
            const float da = fmaf(qz[q], ta.z, fmaf(qy[q], ta.y, fmaf(qx[q], ta.x, ta.w)));
            const float db = fmaf(qz[q], tb.z, fmaf(qy[q], tb.y, fmaf(qx[q], tb.x, tb.w)));
            const float dc = fmaf(qz[q], tc.z, fmaf(qy[q], tc.y, fmaf(qx[q], tc.x, tc.w)));
            const float dd = fmaf(qz[q], td.z, fmaf(qy[q], td.y, fmaf(qx[q], td.x, td.w)));
            m0[q] = fminf(fminf(m0[q], da), db);   // -> v_min3_f32
            m1[q] = fminf(fminf(m1[q], dc), dd);   // -> v_min3_f32
        }
    }

    // --- Cross-wave min combine (add |p|^2 here: commutes with min) ---
    #pragma unroll
    for (int q = 0; q < 4; ++q)
        smin[w][q * 64 + lane] = fminf(m0[q], m1[q]) + pp[q];
    __syncthreads();

    // --- Block-level sum of the 256 per-query mins; single ws write ---
    if (tid < 256) {
        float v = smin[0][tid];
        #pragma unroll
        for (int ww = 1; ww < 16; ++ww)
            v = fminf(v, smin[ww][tid]);
        #pragma unroll
        for (int off = 32; off > 0; off >>= 1)
            v += __shfl_down(v, off);
        if (lane == 0)
            spart[w] = v;              // w in 0..3 here
    }
    __syncthreads();

    if (tid == 0)
        partial[bid] = spart[0] + spart[1] + spart[2] + spart[3];
}

__global__ __launch_bounds__(256) void reduce_kernel(
    const float* __restrict__ partial,
    float* __restrict__ out)
{
    const int tid  = threadIdx.x;
    const int lane = tid & 63;
    const int w    = tid >> 6;
    __shared__ float s[4];

    float v = partial[tid];
    #pragma unroll
    for (int off = 32; off > 0; off >>= 1)
        v += __shfl_down(v, off);
    if (lane == 0) s[w] = v;
    __syncthreads();

    if (tid == 0)
        out[0] = (s[0] + s[1] + s[2] + s[3]) * (1.0f / (float)(BATCH * NPTS));
}

extern "C" void kernel_launch(void* const* d_in, const int* in_sizes, int n_in,
                              void* d_out, int out_size, void* d_ws, size_t ws_size,
                              hipStream_t stream)
{
    const float* pred = (const float*)d_in[0];
    const float* tgt  = (const float*)d_in[1];
    float* out = (float*)d_out;
    float* partial = (float*)d_ws;     // 256 floats, fully rewritten each call

    chamfer_kernel<<<dim3(NBLK), dim3(1024), 0, stream>>>(pred, tgt, partial);
    reduce_kernel<<<dim3(1), dim3(256), 0, stream>>>(partial, out);
}